// Round 2
// baseline (434.536 us; speedup 1.0000x reference)
//
#include <hip/hip_runtime.h>
#include <hip/hip_bf16.h>

// Problem: N=4, L=128 (q & k len), S=64, D=256, H=8. Heads collapse:
// per-head projections share weights and the mask broadcasts over heads,
// so attn is head-independent and out = (attn@v) @ WoSum + bo with
// WoSum[d][e] = sum_h Wo[h*256+d][e].  All I/O fp32; internal compute bf16
// MFMA (16x16x32) with fp32 accumulation.
//
// Pipeline:
//   prep:   WqT/WkT/WvT[e][d] = (bf16)W[d][e]; WoSumT[e][d] = (bf16)sum_h Wo
//   proj:   qp = query@Wq, kp = keys@Wk   -> bf16 [n][l][s][d]
//           vpT = values@Wv stored slice-transposed: vpT[sl][d][k], sl=n*64+s
//   energy: E[sl][q][k] = sum_d qp . kp   (fp32)
//   softmax over k (mask, scale 1/16, masked -> -1e20/16) -> P bf16
//   pv:     O[n][q][s][d] = sum_k P * v
//   out:    out = O @ WoSum + bo          (fp32 out)
// A and B fragments use the same lane->k map so the HW k-permutation cancels;
// D layout: row=(lane>>4)*4+j, col=lane&15 (HW-verified).

using bf16x8 = __attribute__((ext_vector_type(8))) __bf16;
using f32x4  = __attribute__((ext_vector_type(4))) float;

#define MFMA(a, b, c) __builtin_amdgcn_mfma_f32_16x16x32_bf16((a), (b), (c), 0, 0, 0)

__global__ __launch_bounds__(256) void prep_weights(
    const float* __restrict__ Wq, const float* __restrict__ Wk,
    const float* __restrict__ Wv, const float* __restrict__ Wo,
    __bf16* __restrict__ WqT, __bf16* __restrict__ WkT,
    __bf16* __restrict__ WvT, __bf16* __restrict__ WoSumT) {
  int idx = blockIdx.x * 256 + threadIdx.x;   // idx = e*256 + d
  int e = idx >> 8, d = idx & 255;
  WqT[idx] = (__bf16)Wq[d * 256 + e];
  WkT[idx] = (__bf16)Wk[d * 256 + e];
  WvT[idx] = (__bf16)Wv[d * 256 + e];
  float s = 0.f;
#pragma unroll
  for (int h = 0; h < 8; ++h) s += Wo[(h * 256 + d) * 256 + e];
  WoSumT[idx] = (__bf16)s;
}

__device__ __forceinline__ bf16x8 cvt8(const float4 f0, const float4 f1) {
  bf16x8 a;
  a[0] = (__bf16)f0.x; a[1] = (__bf16)f0.y; a[2] = (__bf16)f0.z; a[3] = (__bf16)f0.w;
  a[4] = (__bf16)f1.x; a[5] = (__bf16)f1.y; a[6] = (__bf16)f1.z; a[7] = (__bf16)f1.w;
  return a;
}

// C = X[M=32768, 256](fp32) @ W[256,256] via WT[e][d] (bf16).
// MODE 0: C[r*256+c] bf16 row-major. MODE 1: vpT[(sl*256+c)*128+k] with
// r = ((n*128+k)*64+s), sl = n*64+s.
template <int MODE>
__global__ __launch_bounds__(256) void proj_gemm(
    const float* __restrict__ X, const __bf16* __restrict__ WT,
    __bf16* __restrict__ C) {
  const int lane = threadIdx.x & 63, wave = threadIdx.x >> 6;
  const int lr = lane & 15, g = lane >> 4;
  const int r0 = blockIdx.x * 16;
  const int c0 = blockIdx.y * 64 + wave * 16;
  const float4* __restrict__ arow =
      reinterpret_cast<const float4*>(X + (size_t)(r0 + lr) * 256);
  const bf16x8* __restrict__ brow =
      reinterpret_cast<const bf16x8*>(WT + (size_t)(c0 + lr) * 256);
  f32x4 acc = {0.f, 0.f, 0.f, 0.f};
#pragma unroll
  for (int k8 = 0; k8 < 32; k8 += 4) {   // K=256 in steps of 32
    bf16x8 a = cvt8(arow[2 * (k8 + g)], arow[2 * (k8 + g) + 1]);
    bf16x8 b = brow[k8 + g];
    acc = MFMA(a, b, acc);
  }
#pragma unroll
  for (int j = 0; j < 4; ++j) {
    int r = r0 + 4 * g + j;
    int c = c0 + lr;
    if (MODE == 0) {
      C[(size_t)r * 256 + c] = (__bf16)acc[j];
    } else {
      int n = r >> 13, k = (r >> 6) & 127, s = r & 63;
      int sl = n * 64 + s;
      C[((size_t)sl * 256 + c) * 128 + k] = (__bf16)acc[j];
    }
  }
}

// E[sl][q][k2] = sum_d qp[n,q,s,:] . kp[n,k2,s,:]   (fp32 out)
__global__ __launch_bounds__(256) void energy_gemm(
    const __bf16* __restrict__ qp, const __bf16* __restrict__ kp,
    float* __restrict__ Ebuf) {
  const int lane = threadIdx.x & 63, wave = threadIdx.x >> 6;
  const int lr = lane & 15, g = lane >> 4;
  const int sl = blockIdx.z, n = sl >> 6, s = sl & 63;
  const int q0 = blockIdx.x * 16;
  const int c0 = blockIdx.y * 64 + wave * 16;   // k2 tile
  const __bf16* qb = qp + ((size_t)(n * 128 + q0 + lr) * 64 + s) * 256;
  const __bf16* kb = kp + ((size_t)(n * 128 + c0 + lr) * 64 + s) * 256;
  f32x4 acc = {0.f, 0.f, 0.f, 0.f};
#pragma unroll
  for (int d0 = 0; d0 < 256; d0 += 32) {
    bf16x8 a = *reinterpret_cast<const bf16x8*>(qb + d0 + 8 * g);
    bf16x8 b = *reinterpret_cast<const bf16x8*>(kb + d0 + 8 * g);
    acc = MFMA(a, b, acc);
  }
  float* erow = Ebuf + (size_t)sl * (128 * 128);
#pragma unroll
  for (int j = 0; j < 4; ++j)
    erow[(q0 + 4 * g + j) * 128 + (c0 + lr)] = acc[j];
}

// One wave per row (sl,q): softmax over k=128 with mask + 1/16 scale.
__global__ __launch_bounds__(256) void softmax_kernel(
    const float* __restrict__ Ebuf, const int* __restrict__ mask,
    __bf16* __restrict__ P) {
  const int lane = threadIdx.x & 63, wave = threadIdx.x >> 6;
  const int row = blockIdx.x * 4 + wave;          // row = sl*128 + q
  const int sl = row >> 7, q = row & 127, n = sl >> 6;
  const float* e = Ebuf + (size_t)row * 128;
  const int* m = mask + ((size_t)n * 128 + q) * 128;   // mask[n][0][q][k][0]
  float s0 = m[lane]      ? e[lane] * 0.0625f      : -6.25e18f;  // -1e20/16
  float s1 = m[lane + 64] ? e[lane + 64] * 0.0625f : -6.25e18f;
  float mx = fmaxf(s0, s1);
#pragma unroll
  for (int o = 32; o > 0; o >>= 1) mx = fmaxf(mx, __shfl_xor(mx, o));
  float e0 = __expf(s0 - mx), e1 = __expf(s1 - mx);
  float sum = e0 + e1;
#pragma unroll
  for (int o = 32; o > 0; o >>= 1) sum += __shfl_xor(sum, o);
  float inv = 1.f / sum;
  P[(size_t)row * 128 + lane]      = (__bf16)(e0 * inv);
  P[(size_t)row * 128 + lane + 64] = (__bf16)(e1 * inv);
}

// O[n][q][s][d] = sum_k P[sl][q][k] * vpT[sl][d][k]
__global__ __launch_bounds__(256) void pv_gemm(
    const __bf16* __restrict__ P, const __bf16* __restrict__ vpT,
    __bf16* __restrict__ O) {
  const int lane = threadIdx.x & 63, wave = threadIdx.x >> 6;
  const int lr = lane & 15, g = lane >> 4;
  const int sl = blockIdx.z, n = sl >> 6, s = sl & 63;
  const int q0 = blockIdx.x * 16;
  const int c0 = blockIdx.y * 64 + wave * 16;     // d tile
  const bf16x8* arow =
      reinterpret_cast<const bf16x8*>(P + ((size_t)sl * 128 + q0 + lr) * 128);
  const bf16x8* brow =
      reinterpret_cast<const bf16x8*>(vpT + ((size_t)sl * 256 + c0 + lr) * 128);
  f32x4 acc = {0.f, 0.f, 0.f, 0.f};
#pragma unroll
  for (int k8 = 0; k8 < 16; k8 += 4) {   // K=128
    bf16x8 a = arow[k8 + g];
    bf16x8 b = brow[k8 + g];
    acc = MFMA(a, b, acc);
  }
#pragma unroll
  for (int j = 0; j < 4; ++j) {
    int q = q0 + 4 * g + j;
    O[((size_t)(n * 128 + q) * 64 + s) * 256 + c0 + lr] = (__bf16)acc[j];
  }
}

// out = O[32768,256] @ WoSum + bo   (fp32 out)
__global__ __launch_bounds__(256) void out_gemm(
    const __bf16* __restrict__ O, const __bf16* __restrict__ WoSumT,
    const float* __restrict__ bo, float* __restrict__ out) {
  const int lane = threadIdx.x & 63, wave = threadIdx.x >> 6;
  const int lr = lane & 15, g = lane >> 4;
  const int r0 = blockIdx.x * 16;
  const int c0 = blockIdx.y * 64 + wave * 16;
  const bf16x8* arow =
      reinterpret_cast<const bf16x8*>(O + (size_t)(r0 + lr) * 256);
  const bf16x8* brow =
      reinterpret_cast<const bf16x8*>(WoSumT + (size_t)(c0 + lr) * 256);
  f32x4 acc = {0.f, 0.f, 0.f, 0.f};
#pragma unroll
  for (int k8 = 0; k8 < 32; k8 += 4) {
    bf16x8 a = arow[k8 + g];
    bf16x8 b = brow[k8 + g];
    acc = MFMA(a, b, acc);
  }
  float bias = bo[c0 + lr];
#pragma unroll
  for (int j = 0; j < 4; ++j)
    out[(size_t)(r0 + 4 * g + j) * 256 + c0 + lr] = acc[j] + bias;
}

extern "C" void kernel_launch(void* const* d_in, const int* in_sizes, int n_in,
                              void* d_out, int out_size, void* d_ws, size_t ws_size,
                              hipStream_t stream) {
  const float* values = (const float*)d_in[0];
  const float* keys   = (const float*)d_in[1];
  const float* query  = (const float*)d_in[2];
  const int*   mask   = (const int*)d_in[3];
  const float* Wq     = (const float*)d_in[4];
  const float* Wk     = (const float*)d_in[5];
  const float* Wv     = (const float*)d_in[6];
  const float* Wo     = (const float*)d_in[7];
  const float* bo     = (const float*)d_in[8];
  float* out = (float*)d_out;

  // Workspace carve (~88.5 MB total)
  char* w = (char*)d_ws;
  __bf16* qp     = (__bf16*)w; w += 16777216;   // [N,L,S,D] bf16
  __bf16* kp     = (__bf16*)w; w += 16777216;
  __bf16* vpT    = (__bf16*)w; w += 16777216;   // [sl=256][d=256][k=128]
  float*  Ebuf   = (float*) w; w += 16777216;   // [sl][q=128][k=128] fp32
  __bf16* P      = (__bf16*)w; w += 8388608;    // [sl][q][k] bf16
  __bf16* Obuf   = (__bf16*)w; w += 16777216;   // [N,L,S,D] bf16
  __bf16* WqT    = (__bf16*)w; w += 131072;
  __bf16* WkT    = (__bf16*)w; w += 131072;
  __bf16* WvT    = (__bf16*)w; w += 131072;
  __bf16* WoSumT = (__bf16*)w; w += 131072;

  prep_weights<<<256, 256, 0, stream>>>(Wq, Wk, Wv, Wo, WqT, WkT, WvT, WoSumT);
  proj_gemm<0><<<dim3(2048, 4), 256, 0, stream>>>(query,  WqT, qp);
  proj_gemm<0><<<dim3(2048, 4), 256, 0, stream>>>(keys,   WkT, kp);
  proj_gemm<1><<<dim3(2048, 4), 256, 0, stream>>>(values, WvT, vpT);
  energy_gemm<<<dim3(8, 2, 256), 256, 0, stream>>>(qp, kp, Ebuf);
  softmax_kernel<<<8192, 256, 0, stream>>>(Ebuf, mask, P);
  pv_gemm<<<dim3(8, 4, 256), 256, 0, stream>>>(P, vpT, Obuf);
  out_gemm<<<dim3(2048, 4), 256, 0, stream>>>(Obuf, WoSumT, bo, out);
}

// Round 4
// 198.902 us; speedup vs baseline: 2.1847x; 2.1847x over previous
//
#include <hip/hip_runtime.h>
#include <hip/hip_bf16.h>

// N=4, L=128, S=64, D=256, H=8. Heads collapse (shared per-head weights +
// head-broadcast mask) => out = softmax((Xq Wq)(Xk Wk)^T/16 + mask) (Xv Wv) @ WoSum + bo,
// computed independently per slice sl = n*64+s (256 slices of [128,256]).
//
// All MFMA operands use "pack" (fragment-major) layouts so every global
// fragment load is 64 lanes x 16B coalesced:
//   pack tile = [tile][k8][lane=64][j=8]; lane l holds row (l&15) of the
//   16-row tile, k-chunk k8*32 + (l>>4)*8 + j.  A and B share the lane->k map
//   so the HW k-permutation cancels; D layout row=4*(lane>>4)+j, col=lane&15.
//
// Kernels:
//  1) prep_pack:  Wq/Wk/Wv -> wpacks; WoSum (sum over heads) -> wopack (bf16)
//  2) proj<MODE>: X fp32 -> LDS (bf16, XOR-swizzled) -> MFMA -> q/k/v packs
//  3) attn:       per-slice QK^T -> masked softmax -> PV, S/P in LDS -> opack
//  4) out_gemm:   opack @ wopack + bo -> out (fp32)

using bf16x4 = __attribute__((ext_vector_type(4))) __bf16;
using bf16x8 = __attribute__((ext_vector_type(8))) __bf16;
using f32x4  = __attribute__((ext_vector_type(4))) float;

#define MFMA(a, b, c) __builtin_amdgcn_mfma_f32_16x16x32_bf16((a), (b), (c), 0, 0, 0)

// ---------------------------------------------------------------- prep packs
// pack[ct][k8][lane][j] = W[d][e], e = ct*16+(lane&15), d = k8*32+(lane>>4)*8+j
__global__ __launch_bounds__(256) void prep_pack(
    const float* __restrict__ Wq, const float* __restrict__ Wk,
    const float* __restrict__ Wv, const float* __restrict__ Wo,
    __bf16* __restrict__ wqp, __bf16* __restrict__ wkp,
    __bf16* __restrict__ wvp, __bf16* __restrict__ wop) {
  int idx = blockIdx.x * 256 + threadIdx.x;       // [0, 65536)
  int j = idx & 7, lane = (idx >> 3) & 63, k8 = (idx >> 9) & 7, ct = idx >> 12;
  int e = ct * 16 + (lane & 15);
  int d = k8 * 32 + (lane >> 4) * 8 + j;
  wqp[idx] = (__bf16)Wq[d * 256 + e];
  wkp[idx] = (__bf16)Wk[d * 256 + e];
  wvp[idx] = (__bf16)Wv[d * 256 + e];
  float s = 0.f;
#pragma unroll
  for (int h = 0; h < 8; ++h) s += Wo[(h * 256 + d) * 256 + e];
  wop[idx] = (__bf16)s;
}

// ---------------------------------------------------------------- projection
// Block: 256 thr (4 waves), 64 rows x 256 cols, K=256 in one shot.
// MODE 0: write q/k pack  pack[sl][qt=q>>4][k8=d>>5][lane][j]   (rows keyed by q)
// MODE 1: write v pack    pack[sl][dt=d>>4][kk8=k2>>5][lane][j] (rows keyed by d)
template <int MODE>
__global__ __launch_bounds__(256) void proj(
    const float* __restrict__ X, const __bf16* __restrict__ wpack,
    __bf16* __restrict__ out) {
  __shared__ __bf16 As[64 * 256];                 // 32KB, XOR-swizzled
  const int t = threadIdx.x, lane = t & 63, w = t >> 6;
  const int lr = lane & 15, g = lane >> 4;
  const int r0 = blockIdx.x * 64;

  // stage: 64KB contiguous fp32, convert to bf16, swizzled ds_write.
  // 64 float4 per row (256 fp32); each wave iteration covers one full row.
  const float4* Xv = reinterpret_cast<const float4*>(X + (size_t)r0 * 256);
#pragma unroll
  for (int i = 0; i < 16; ++i) {
    int f = i * 256 + t;                          // float4 index in [0,4096)
    float4 v = Xv[f];
    int row = f >> 6, c4 = f & 63;                // FIX: 64 float4 per row
    bf16x4 b;
    b[0] = (__bf16)v.x; b[1] = (__bf16)v.y; b[2] = (__bf16)v.z; b[3] = (__bf16)v.w;
    *reinterpret_cast<bf16x4*>(
        (char*)As + row * 512 + ((c4 * 8) ^ ((row & 7) << 4))) = b;
  }
  __syncthreads();

  // hoist A fragments: wave w owns LDS rows w*16 .. w*16+15
  const int arow = w * 16 + lr;
  bf16x8 af[8];
#pragma unroll
  for (int k8 = 0; k8 < 8; ++k8)
    af[k8] = *reinterpret_cast<const bf16x8*>(
        (char*)As + arow * 512 + ((k8 * 64 + g * 16) ^ ((arow & 7) << 4)));

  const bf16x8* wp = reinterpret_cast<const bf16x8*>(wpack);
#pragma unroll
  for (int ct = 0; ct < 16; ++ct) {
    f32x4 acc = {0.f, 0.f, 0.f, 0.f};
#pragma unroll
    for (int k8 = 0; k8 < 8; ++k8)
      acc = MFMA(af[k8], wp[(ct * 8 + k8) * 64 + lane], acc);
    int c = ct * 16 + lr;
#pragma unroll
    for (int j = 0; j < 4; ++j) {
      int r = r0 + w * 16 + 4 * g + j;            // global row in [0,32768)
      int n = r >> 13, q = (r >> 6) & 127, s = r & 63;
      size_t sl = (size_t)(n * 64 + s);
      size_t addr;
      if (MODE == 0)        // rows by q, k-dim = d(c)
        addr = (((sl * 8 + (q >> 4)) * 8 + (c >> 5)) * 64 +
                ((q & 15) + 16 * ((c >> 3) & 3))) * 8 + (c & 7);
      else                  // rows by d(c), k-dim = k2(q)
        addr = (((sl * 16 + (c >> 4)) * 4 + (q >> 5)) * 64 +
                ((c & 15) + 16 * ((q >> 3) & 3))) * 8 + (q & 7);
      out[addr] = (__bf16)acc[j];
    }
  }
}

// ---------------------------------------------------------------- fused attn
// One block (512 thr, 8 waves) per slice. LDS: S fp32 [128][128] (64KB) +
// P bf16 [128][128] (32KB), both XOR-swizzled with ((row&7)<<4).
__global__ __launch_bounds__(512) void attn(
    const __bf16* __restrict__ qpack, const __bf16* __restrict__ kpack,
    const __bf16* __restrict__ vpack, const int* __restrict__ mask,
    __bf16* __restrict__ opack) {
  extern __shared__ char smem[];
  float*  Sb = reinterpret_cast<float*>(smem);            // 64KB
  char*   Pb = smem + 65536;                              // 32KB bf16
  const int t = threadIdx.x, lane = t & 63, w = t >> 6;
  const int lr = lane & 15, g = lane >> 4;
  const int sl = blockIdx.x, n = sl >> 6, s = sl & 63;

  const bf16x8* qp = reinterpret_cast<const bf16x8*>(qpack);
  const bf16x8* kp = reinterpret_cast<const bf16x8*>(kpack);
  const bf16x8* vp = reinterpret_cast<const bf16x8*>(vpack);

  // ---- phase 1: S = Q K^T (wave w: q rows 16w..16w+15, all 128 k2 cols)
  bf16x8 qa[8];
#pragma unroll
  for (int k8 = 0; k8 < 8; ++k8)
    qa[k8] = qp[(((size_t)sl * 8 + w) * 8 + k8) * 64 + lane];
#pragma unroll
  for (int ct = 0; ct < 8; ++ct) {
    f32x4 acc = {0.f, 0.f, 0.f, 0.f};
#pragma unroll
    for (int k8 = 0; k8 < 8; ++k8)
      acc = MFMA(qa[k8], kp[(((size_t)sl * 8 + ct) * 8 + k8) * 64 + lane], acc);
    int col = ct * 16 + lr;
#pragma unroll
    for (int j = 0; j < 4; ++j) {
      int row = w * 16 + 4 * g + j;
      *reinterpret_cast<float*>(
          (char*)Sb + row * 512 + ((col * 4) ^ ((row & 7) << 4))) = acc[j];
    }
  }
  __syncthreads();

  // ---- phase 2: masked softmax over k (wave w: rows 16w..16w+15)
#pragma unroll 1
  for (int rr = 0; rr < 16; ++rr) {
    int r = w * 16 + rr;
    int xr = (r & 7) << 4;
    float v0 = *reinterpret_cast<float*>((char*)Sb + r * 512 + ((lane * 4) ^ xr));
    float v1 = *reinterpret_cast<float*>((char*)Sb + r * 512 + (((lane + 64) * 4) ^ xr));
    const int* mrow = mask + ((size_t)n * 128 + r) * 128;
    float s0 = mrow[lane]      ? v0 * 0.0625f : -6.25e18f;   // -1e20/16
    float s1 = mrow[lane + 64] ? v1 * 0.0625f : -6.25e18f;
    float mx = fmaxf(s0, s1);
#pragma unroll
    for (int o = 32; o > 0; o >>= 1) mx = fmaxf(mx, __shfl_xor(mx, o));
    float e0 = __expf(s0 - mx), e1 = __expf(s1 - mx);
    float sum = e0 + e1;
#pragma unroll
    for (int o = 32; o > 0; o >>= 1) sum += __shfl_xor(sum, o);
    float inv = 1.f / sum;
    *reinterpret_cast<__bf16*>(Pb + r * 256 + ((2 * lane) ^ xr)) = (__bf16)(e0 * inv);
    *reinterpret_cast<__bf16*>(Pb + r * 256 + ((2 * (lane + 64)) ^ xr)) = (__bf16)(e1 * inv);
  }
  __syncthreads();

  // ---- phase 3: O = P V  (wave w: q rows 16w..16w+15, all 256 d cols)
  const int prow = w * 16 + lr;
  bf16x8 pa[4];
#pragma unroll
  for (int kk8 = 0; kk8 < 4; ++kk8)
    pa[kk8] = *reinterpret_cast<const bf16x8*>(
        Pb + prow * 256 + ((kk8 * 64 + g * 16) ^ ((prow & 7) << 4)));
#pragma unroll
  for (int dt = 0; dt < 16; ++dt) {
    f32x4 acc = {0.f, 0.f, 0.f, 0.f};
#pragma unroll
    for (int kk8 = 0; kk8 < 4; ++kk8)
      acc = MFMA(pa[kk8], vp[(((size_t)sl * 16 + dt) * 4 + kk8) * 64 + lane], acc);
    int d = dt * 16 + lr;
#pragma unroll
    for (int j = 0; j < 4; ++j) {
      int q = w * 16 + 4 * g + j;
      size_t R = ((size_t)(n * 128 + q) * 64 + s);
      size_t addr = (((R >> 4) * 8 + (d >> 5)) * 64 +
                     ((R & 15) + 16 * ((d >> 3) & 3))) * 8 + (d & 7);
      opack[addr] = (__bf16)acc[j];
    }
  }
}

// ---------------------------------------------------------------- out proj
// out[R][e] = sum_d O[R][d] * WoSum[d][e] + bo[e]; A from opack (coalesced),
// B from wopack (coalesced). No LDS. Block: 256 thr, 64 rows x 256 cols.
__global__ __launch_bounds__(256) void out_gemm(
    const __bf16* __restrict__ opack, const __bf16* __restrict__ wopack,
    const float* __restrict__ bo, float* __restrict__ out) {
  const int t = threadIdx.x, lane = t & 63, w = t >> 6;
  const int lr = lane & 15, g = lane >> 4;
  const int R0 = blockIdx.x * 64;
  const bf16x8* op = reinterpret_cast<const bf16x8*>(opack);
  const bf16x8* wp = reinterpret_cast<const bf16x8*>(wopack);
  const size_t Rt = (size_t)(R0 >> 4) + w;
  bf16x8 oa[8];
#pragma unroll
  for (int k8 = 0; k8 < 8; ++k8)
    oa[k8] = op[(Rt * 8 + k8) * 64 + lane];
#pragma unroll
  for (int ct = 0; ct < 16; ++ct) {
    f32x4 acc = {0.f, 0.f, 0.f, 0.f};
#pragma unroll
    for (int k8 = 0; k8 < 8; ++k8)
      acc = MFMA(oa[k8], wp[(ct * 8 + k8) * 64 + lane], acc);
    int c = ct * 16 + lr;
    float bias = bo[c];
#pragma unroll
    for (int j = 0; j < 4; ++j)
      out[(size_t)(R0 + w * 16 + 4 * g + j) * 256 + c] = acc[j] + bias;
  }
}

extern "C" void kernel_launch(void* const* d_in, const int* in_sizes, int n_in,
                              void* d_out, int out_size, void* d_ws, size_t ws_size,
                              hipStream_t stream) {
  const float* values = (const float*)d_in[0];
  const float* keys   = (const float*)d_in[1];
  const float* query  = (const float*)d_in[2];
  const int*   mask   = (const int*)d_in[3];
  const float* Wq     = (const float*)d_in[4];
  const float* Wk     = (const float*)d_in[5];
  const float* Wv     = (const float*)d_in[6];
  const float* Wo     = (const float*)d_in[7];
  const float* bo     = (const float*)d_in[8];
  float* out = (float*)d_out;

  char* w = (char*)d_ws;
  __bf16* qpack = (__bf16*)w; w += 16777216;   // [256 sl][8 qt][8 k8][64][8]
  __bf16* kpack = (__bf16*)w; w += 16777216;   // [256 sl][8 kt][8 k8][64][8]
  __bf16* vpack = (__bf16*)w; w += 16777216;   // [256 sl][16 dt][4 kk8][64][8]
  __bf16* opack = (__bf16*)w; w += 16777216;   // [2048 Rt][8 k8][64][8]
  __bf16* wqp   = (__bf16*)w; w += 131072;     // [16 ct][8 k8][64][8]
  __bf16* wkp   = (__bf16*)w; w += 131072;
  __bf16* wvp   = (__bf16*)w; w += 131072;
  __bf16* wop   = (__bf16*)w; w += 131072;

  prep_pack<<<256, 256, 0, stream>>>(Wq, Wk, Wv, Wo, wqp, wkp, wvp, wop);
  proj<0><<<512, 256, 0, stream>>>(query,  wqp, qpack);
  proj<0><<<512, 256, 0, stream>>>(keys,   wkp, kpack);
  proj<1><<<512, 256, 0, stream>>>(values, wvp, vpack);
  attn<<<256, 512, 98304, stream>>>(qpack, kpack, vpack, mask, opack);
  out_gemm<<<512, 256, 0, stream>>>(opack, wop, bo, out);
}

// Round 5
// 104.363 us; speedup vs baseline: 4.1637x; 1.9059x over previous
//
#include <hip/hip_runtime.h>
#include <hip/hip_bf16.h>

// N=4, L=128, S=64, D=256, H=8. Heads collapse (shared per-head weights +
// head-broadcast mask) => out = softmax((Xq Wq)(Xk Wk)^T/16 + mask)(Xv Wv) @ WoSum + bo,
// independent per slice sl = n*64+s (256 slices of [128,256]).
//
// Pack (fragment-major) layouts, all global fragment I/O coalesced 64x16B:
//   qpack/kpack: [sl][qt(8)][k8(8)][lane(64)][j(8)]  (rows=q, contraction=d)
//   vpack:       [sl][dt(16)][kk8(4)][lane][j]       (rows=d, contraction=k2)
//   w*p/wop:     [ct(16)][k8(8)][lane][j]            (rows=e_out, contraction=d_in)
// lane l = row (l&15) of 16-row tile, k-chunk k8*32+(l>>4)*8+j. A/B share the
// lane->k map (HW k-permutation cancels); D layout row=4*(lane>>4)+j, col=lane&15.
//
// Producers assemble pack tiles in a wave-private LDS image, then stream
// contiguous chunks to global (fixes cross-block false sharing / partial-line
// RMW that pinned round-4 proj at 48.5us).

using bf16x4 = __attribute__((ext_vector_type(4))) __bf16;
using bf16x8 = __attribute__((ext_vector_type(8))) __bf16;
using f32x4  = __attribute__((ext_vector_type(4))) float;

#define MFMA(a, b, c) __builtin_amdgcn_mfma_f32_16x16x32_bf16((a), (b), (c), 0, 0, 0)

// ---------------------------------------------------------------- prep packs
__global__ __launch_bounds__(256) void prep_pack(
    const float* __restrict__ Wq, const float* __restrict__ Wk,
    const float* __restrict__ Wv, const float* __restrict__ Wo,
    __bf16* __restrict__ wqp, __bf16* __restrict__ wkp,
    __bf16* __restrict__ wvp, __bf16* __restrict__ wop) {
  int idx = blockIdx.x * 256 + threadIdx.x;       // [0, 65536)
  int j = idx & 7, lane = (idx >> 3) & 63, k8 = (idx >> 9) & 7, ct = idx >> 12;
  int e = ct * 16 + (lane & 15);
  int d = k8 * 32 + (lane >> 4) * 8 + j;
  wqp[idx] = (__bf16)Wq[d * 256 + e];
  wkp[idx] = (__bf16)Wk[d * 256 + e];
  wvp[idx] = (__bf16)Wv[d * 256 + e];
  float s = 0.f;
#pragma unroll
  for (int h = 0; h < 8; ++h) s += Wo[(h * 256 + d) * 256 + e];
  wop[idx] = (__bf16)s;
}

// ---------------------------------------------------------------- q/k proj
// Block = one (slice, which). 512 thr / 8 waves. LDS 64KB: staged X slice
// (swizzled), later per-wave pack image (aliases the wave's consumed rows).
__global__ __launch_bounds__(512) void projqk(
    const float* __restrict__ Xq, const float* __restrict__ Xk,
    const __bf16* __restrict__ wqp, const __bf16* __restrict__ wkp,
    __bf16* __restrict__ qpack, __bf16* __restrict__ kpack) {
  extern __shared__ char lds[];
  const int t = threadIdx.x, lane = t & 63, w = t >> 6;
  const int lr = lane & 15, g = lane >> 4;
  const int sl = blockIdx.x, n = sl >> 6, s = sl & 63;
  const float* X;  const __bf16* wpk;  __bf16* opk;
  if (blockIdx.y == 0) { X = Xq; wpk = wqp; opk = qpack; }
  else                 { X = Xk; wpk = wkp; opk = kpack; }

  // stage 128 rows (l=q), row base (n*8192 + l*64 + s)*256, coalesced 1KB/wave
#pragma unroll
  for (int i = 0; i < 16; ++i) {
    int f = i * 512 + t;                          // [0, 8192)
    int row = f >> 6, c4 = f & 63;
    float4 v = *reinterpret_cast<const float4*>(
        X + ((size_t)(n * 8192 + row * 64 + s)) * 256 + c4 * 4);
    bf16x4 b; b[0]=(__bf16)v.x; b[1]=(__bf16)v.y; b[2]=(__bf16)v.z; b[3]=(__bf16)v.w;
    *reinterpret_cast<bf16x4*>(lds + row * 512 + ((c4 * 8) ^ ((row & 7) << 4))) = b;
  }
  __syncthreads();

  // wave w owns q rows w*16..w*16+15 (A) and image bytes [w*8192, +8192)
  const int arow = w * 16 + lr;
  bf16x8 af[8];
#pragma unroll
  for (int k8 = 0; k8 < 8; ++k8)
    af[k8] = *reinterpret_cast<const bf16x8*>(
        lds + arow * 512 + ((k8 * 64 + g * 16) ^ ((arow & 7) << 4)));

  const bf16x8* wp = reinterpret_cast<const bf16x8*>(wpk);
  char* img = lds + w * 8192;
#pragma unroll
  for (int ct = 0; ct < 16; ++ct) {
    f32x4 acc = {0.f, 0.f, 0.f, 0.f};
#pragma unroll
    for (int k8 = 0; k8 < 8; ++k8)
      acc = MFMA(af[k8], wp[(ct * 8 + k8) * 64 + lane], acc);
    // element (q&15 = 4g+j, c = ct*16+lr) -> [k8t=c>>5][(q&15)+16*((c>>3)&3)][c&7]
    int base = ((ct >> 1) * 64 + 16 * ((ct * 2 + (lr >> 3)) & 3) + 4 * g) * 8 + (lr & 7);
#pragma unroll
    for (int j = 0; j < 4; ++j)
      *reinterpret_cast<__bf16*>(img + (base + j * 8) * 2) = (__bf16)acc[j];
  }
  // stream the wave's contiguous 8KB pack tile
  __bf16* dst = opk + (size_t)sl * 32768 + w * 4096;
#pragma unroll
  for (int it = 0; it < 8; ++it)
    *reinterpret_cast<bf16x8*>(dst + it * 512 + lane * 8) =
        *reinterpret_cast<const bf16x8*>(img + it * 1024 + lane * 16);
}

// ---------------------------------------------------------------- v proj
// Block = (slice, k-half). LDS: 32KB stage (64 k2-rows) + 32KB image (separate
// -> no extra barrier). A = weight rows (d_out), B = X rows (k2) from LDS.
__global__ __launch_bounds__(512) void projv(
    const float* __restrict__ Xv, const __bf16* __restrict__ wvp,
    __bf16* __restrict__ vpack) {
  extern __shared__ char lds[];
  char* img = lds + 32768;
  const int t = threadIdx.x, lane = t & 63, w = t >> 6;
  const int lr = lane & 15, g = lane >> 4;
  const int sl = blockIdx.x, n = sl >> 6, s = sl & 63;
  const int kh = blockIdx.y;                      // k2 in [kh*64, kh*64+64)

#pragma unroll
  for (int i = 0; i < 8; ++i) {
    int f = i * 512 + t;                          // [0, 4096)
    int row = f >> 6, c4 = f & 63;
    float4 v = *reinterpret_cast<const float4*>(
        Xv + ((size_t)(n * 8192 + (kh * 64 + row) * 64 + s)) * 256 + c4 * 4);
    bf16x4 b; b[0]=(__bf16)v.x; b[1]=(__bf16)v.y; b[2]=(__bf16)v.z; b[3]=(__bf16)v.w;
    *reinterpret_cast<bf16x4*>(lds + row * 512 + ((c4 * 8) ^ ((row & 7) << 4))) = b;
  }
  __syncthreads();

  const bf16x8* wp = reinterpret_cast<const bf16x8*>(wvp);
#pragma unroll
  for (int dth = 0; dth < 2; ++dth) {
    const int dt = 2 * w + dth;
    bf16x8 wf[8];
#pragma unroll
    for (int k8 = 0; k8 < 8; ++k8) wf[k8] = wp[(dt * 8 + k8) * 64 + lane];
#pragma unroll
    for (int ct = 0; ct < 4; ++ct) {
      const int brow = ct * 16 + lr;
      f32x4 acc = {0.f, 0.f, 0.f, 0.f};
#pragma unroll
      for (int k8 = 0; k8 < 8; ++k8) {
        bf16x8 xf = *reinterpret_cast<const bf16x8*>(
            lds + brow * 512 + ((k8 * 64 + g * 16) ^ ((brow & 7) << 4)));
        acc = MFMA(wf[k8], xf, acc);
      }
      // element (d&15 = 4g+j, k2loc = ct*16+lr)
      int base = ((dt * 2 + (ct >> 1)) * 64 +
                  16 * ((ct * 2 + (lr >> 3)) & 3) + 4 * g) * 8 + (lr & 7);
#pragma unroll
      for (int j = 0; j < 4; ++j)
        *reinterpret_cast<__bf16*>(img + (base + j * 8) * 2) = (__bf16)acc[j];
    }
  }
  // stream 4 contiguous 1KB chunks: [sl][dt][kk8 = kh*2 + kk8loc]
#pragma unroll
  for (int c = 0; c < 4; ++c) {
    int dth = c >> 1, kk8loc = c & 1, dt = 2 * w + dth;
    __bf16* dst = vpack + ((((size_t)sl * 16 + dt) * 4) + kh * 2 + kk8loc) * 512;
    *reinterpret_cast<bf16x8*>(dst + lane * 8) =
        *reinterpret_cast<const bf16x8*>(img + (size_t)(w * 4 + c) * 1024 + lane * 16);
  }
}

// ---------------------------------------------------------------- attn + out
// One block (512 thr) per slice. All LDS traffic is wave-local (S, P, O-image
// all partitioned by the wave's 16 q-rows) -> zero barriers.
// LDS: S fp32 [128][128] 64KB (later O-image) + P bf16 [128][128] 32KB.
__global__ __launch_bounds__(512) void attn_out(
    const __bf16* __restrict__ qpack, const __bf16* __restrict__ kpack,
    const __bf16* __restrict__ vpack, const int* __restrict__ mask,
    const __bf16* __restrict__ wop, const float* __restrict__ bo,
    float* __restrict__ out) {
  extern __shared__ char smem[];
  float* Sb = reinterpret_cast<float*>(smem);     // 64KB
  char*  Pb = smem + 65536;                       // 32KB
  const int t = threadIdx.x, lane = t & 63, w = t >> 6;
  const int lr = lane & 15, g = lane >> 4;
  const int sl = blockIdx.x, n = sl >> 6, s = sl & 63;

  const bf16x8* qp = reinterpret_cast<const bf16x8*>(qpack);
  const bf16x8* kp = reinterpret_cast<const bf16x8*>(kpack);
  const bf16x8* vp = reinterpret_cast<const bf16x8*>(vpack);
  const bf16x8* wpo = reinterpret_cast<const bf16x8*>(wop);

  // phase 1: S = Q K^T
  bf16x8 qa[8];
#pragma unroll
  for (int k8 = 0; k8 < 8; ++k8)
    qa[k8] = qp[(((size_t)sl * 8 + w) * 8 + k8) * 64 + lane];
#pragma unroll
  for (int ct = 0; ct < 8; ++ct) {
    f32x4 acc = {0.f, 0.f, 0.f, 0.f};
#pragma unroll
    for (int k8 = 0; k8 < 8; ++k8)
      acc = MFMA(qa[k8], kp[(((size_t)sl * 8 + ct) * 8 + k8) * 64 + lane], acc);
    int col = ct * 16 + lr;
#pragma unroll
    for (int j = 0; j < 4; ++j) {
      int row = w * 16 + 4 * g + j;
      *reinterpret_cast<float*>(
          (char*)Sb + row * 512 + ((col * 4) ^ ((row & 7) << 4))) = acc[j];
    }
  }

  // phase 2: masked softmax over k (wave-local rows)
#pragma unroll 1
  for (int rr = 0; rr < 16; ++rr) {
    int r = w * 16 + rr;
    int xr = (r & 7) << 4;
    float v0 = *reinterpret_cast<float*>((char*)Sb + r * 512 + ((lane * 4) ^ xr));
    float v1 = *reinterpret_cast<float*>((char*)Sb + r * 512 + (((lane + 64) * 4) ^ xr));
    const int* mrow = mask + ((size_t)n * 128 + r) * 128;
    float s0 = mrow[lane]      ? v0 * 0.0625f : -6.25e18f;   // -1e20/16
    float s1 = mrow[lane + 64] ? v1 * 0.0625f : -6.25e18f;
    float mx = fmaxf(s0, s1);
#pragma unroll
    for (int o = 32; o > 0; o >>= 1) mx = fmaxf(mx, __shfl_xor(mx, o));
    float e0 = __expf(s0 - mx), e1 = __expf(s1 - mx);
    float sum = e0 + e1;
#pragma unroll
    for (int o = 32; o > 0; o >>= 1) sum += __shfl_xor(sum, o);
    float inv = 1.f / sum;
    *reinterpret_cast<__bf16*>(Pb + r * 256 + ((2 * lane) ^ xr)) = (__bf16)(e0 * inv);
    *reinterpret_cast<__bf16*>(Pb + r * 256 + ((2 * (lane + 64)) ^ xr)) = (__bf16)(e1 * inv);
  }

  // phase 3: O = P V -> wave-private pack image (reuses the wave's S rows)
  const int prow = w * 16 + lr;
  bf16x8 pa[4];
#pragma unroll
  for (int kk8 = 0; kk8 < 4; ++kk8)
    pa[kk8] = *reinterpret_cast<const bf16x8*>(
        Pb + prow * 256 + ((kk8 * 64 + g * 16) ^ ((prow & 7) << 4)));
  char* img = (char*)Sb + w * 8192;
#pragma unroll
  for (int dt = 0; dt < 16; ++dt) {
    f32x4 acc = {0.f, 0.f, 0.f, 0.f};
#pragma unroll
    for (int kk8 = 0; kk8 < 4; ++kk8)
      acc = MFMA(pa[kk8], vp[(((size_t)sl * 16 + dt) * 4 + kk8) * 64 + lane], acc);
    int base = ((dt >> 1) * 64 + 16 * ((dt * 2 + (lr >> 3)) & 3) + 4 * g) * 8 + (lr & 7);
#pragma unroll
    for (int j = 0; j < 4; ++j)
      *reinterpret_cast<__bf16*>(img + (base + j * 8) * 2) = (__bf16)acc[j];
  }

  // phase 4: out = O @ WoSum + bo ; linear image read IS the A-fragment layout
  bf16x8 oa[8];
#pragma unroll
  for (int k8 = 0; k8 < 8; ++k8)
    oa[k8] = *reinterpret_cast<const bf16x8*>(img + k8 * 1024 + lane * 16);
#pragma unroll
  for (int ct = 0; ct < 16; ++ct) {
    f32x4 acc = {0.f, 0.f, 0.f, 0.f};
#pragma unroll
    for (int k8 = 0; k8 < 8; ++k8)
      acc = MFMA(oa[k8], wpo[(ct * 8 + k8) * 64 + lane], acc);
    int e = ct * 16 + lr;
    float bias = bo[e];
#pragma unroll
    for (int j = 0; j < 4; ++j) {
      int q = w * 16 + 4 * g + j;
      out[((size_t)n * 8192 + q * 64 + s) * 256 + e] = acc[j] + bias;
    }
  }
}

extern "C" void kernel_launch(void* const* d_in, const int* in_sizes, int n_in,
                              void* d_out, int out_size, void* d_ws, size_t ws_size,
                              hipStream_t stream) {
  const float* values = (const float*)d_in[0];
  const float* keys   = (const float*)d_in[1];
  const float* query  = (const float*)d_in[2];
  const int*   mask   = (const int*)d_in[3];
  const float* Wq     = (const float*)d_in[4];
  const float* Wk     = (const float*)d_in[5];
  const float* Wv     = (const float*)d_in[6];
  const float* Wo     = (const float*)d_in[7];
  const float* bo     = (const float*)d_in[8];
  float* out = (float*)d_out;

  char* w = (char*)d_ws;
  __bf16* qpack = (__bf16*)w; w += 16777216;   // [256 sl][8 qt][8 k8][64][8]
  __bf16* kpack = (__bf16*)w; w += 16777216;
  __bf16* vpack = (__bf16*)w; w += 16777216;   // [256 sl][16 dt][4 kk8][64][8]
  __bf16* wqp   = (__bf16*)w; w += 131072;     // [16 ct][8 k8][64][8]
  __bf16* wkp   = (__bf16*)w; w += 131072;
  __bf16* wvp   = (__bf16*)w; w += 131072;
  __bf16* wop   = (__bf16*)w; w += 131072;

  prep_pack<<<256, 256, 0, stream>>>(Wq, Wk, Wv, Wo, wqp, wkp, wvp, wop);
  projqk<<<dim3(256, 2), 512, 65536, stream>>>(query, keys, wqp, wkp, qpack, kpack);
  projv<<<dim3(256, 2), 512, 65536, stream>>>(values, wvp, vpack);
  attn_out<<<256, 512, 98304, stream>>>(qpack, kpack, vpack, mask, wop, bo, out);
}

// Round 6
// 57.633 us; speedup vs baseline: 7.5397x; 1.8108x over previous
//
#include <hip/hip_runtime.h>
#include <hip/hip_bf16.h>

// N=4, L=128, S=64, D=256, H=8. Heads collapse => per slice sl=n*64+s:
//   out = softmax((Xq Wq)(Xk Wk)^T/16 + mask) (Xv Wv) @ WoSum + bo
// ONE fused kernel, one block (512 thr / 8 waves, 160KB LDS) per slice.
// All MFMA B-operands come from LDS; weights are held in registers (A-side)
// for the three input projections. Frag convention everywhere:
//   [tile][k8-chunk][lane(64)][j(8)]: lane l = row/col (l&15) of the 16-tile,
//   k-chunk k8*32+(l>>4)*8+j. A/B share the lane->k map (HW perm cancels);
//   D layout row=4*(lane>>4)+j, col=lane&15.
// LDS: A [0,64K) staged X (swizzled rows) -> later v-pack kk8{2,3} in A-low
//      B [64K,128K) q-image -> k-pack -> P(per-wave 4K) -> O-image(per-wave 8K)
//      C [128K,160K) v-pack kk8{0,1}

using bf16x4 = __attribute__((ext_vector_type(4))) __bf16;
using bf16x8 = __attribute__((ext_vector_type(8))) __bf16;
using f32x4  = __attribute__((ext_vector_type(4))) float;

#define MFMA(a, b, c) __builtin_amdgcn_mfma_f32_16x16x32_bf16((a), (b), (c), 0, 0, 0)

// ---------------------------------------------------------------- prep packs
// pack[ct][k8][lane][j] = W[d][e], e = ct*16+(lane&15), d = k8*32+(lane>>4)*8+j
// (chunk dim = W row = contraction; slot dim = W col = output)
__global__ __launch_bounds__(256) void prep_pack(
    const float* __restrict__ Wq, const float* __restrict__ Wk,
    const float* __restrict__ Wv, const float* __restrict__ Wo,
    __bf16* __restrict__ wqp, __bf16* __restrict__ wkp,
    __bf16* __restrict__ wvp, __bf16* __restrict__ wop) {
  int idx = blockIdx.x * 256 + threadIdx.x;       // [0, 65536)
  int j = idx & 7, lane = (idx >> 3) & 63, k8 = (idx >> 9) & 7, ct = idx >> 12;
  int e = ct * 16 + (lane & 15);
  int d = k8 * 32 + (lane >> 4) * 8 + j;
  wqp[idx] = (__bf16)Wq[d * 256 + e];
  wkp[idx] = (__bf16)Wk[d * 256 + e];
  wvp[idx] = (__bf16)Wv[d * 256 + e];
  float s = 0.f;
#pragma unroll
  for (int h = 0; h < 8; ++h) s += Wo[(h * 256 + d) * 256 + e];
  wop[idx] = (__bf16)s;
}

// ---------------------------------------------------------------- fused
__global__ __launch_bounds__(512) void fused_attn(
    const float* __restrict__ Xv, const float* __restrict__ Xk,
    const float* __restrict__ Xq, const int* __restrict__ mask,
    const __bf16* __restrict__ wqp, const __bf16* __restrict__ wkp,
    const __bf16* __restrict__ wvp, const __bf16* __restrict__ wop,
    const float* __restrict__ bo, float* __restrict__ out) {
  extern __shared__ char lds[];
  char* Areg = lds;                // 64KB
  char* Breg = lds + 65536;        // 64KB
  char* Creg = lds + 131072;       // 32KB
  const int t = threadIdx.x, lane = t & 63, w = t >> 6;
  const int lr = lane & 15, g = lane >> 4;
  const int sl = blockIdx.x, n = sl >> 6, s = sl & 63;

  // stage a 128-row [row][256] fp32 slice -> Areg as swizzled bf16
  auto stageX = [&](const float* __restrict__ X) {
#pragma unroll
    for (int i = 0; i < 16; ++i) {
      int f = i * 512 + t;
      int row = f >> 6, c4 = f & 63;
      float4 v = *reinterpret_cast<const float4*>(
          X + ((size_t)(n * 8192 + row * 64 + s)) * 256 + c4 * 4);
      bf16x4 b; b[0]=(__bf16)v.x; b[1]=(__bf16)v.y; b[2]=(__bf16)v.z; b[3]=(__bf16)v.w;
      *reinterpret_cast<bf16x4*>(Areg + row * 512 + ((c4 * 8) ^ ((row & 7) << 4))) = b;
    }
  };
  // weights-in-regs projection; D[d=32w+16dth+4g+j][col=ct*16+lr]; image to Breg
  // in frag layout [ct][k8=w][slot=lr+16*(2dth+(g>>1))][jj], jj contiguous in j.
  auto projQK = [&](const __bf16* __restrict__ wpk) {
    const bf16x8* wp = reinterpret_cast<const bf16x8*>(wpk);
#pragma unroll
    for (int dth = 0; dth < 2; ++dth) {
      int dt = 2 * w + dth;
      bf16x8 wf[8];
#pragma unroll
      for (int k8 = 0; k8 < 8; ++k8) wf[k8] = wp[(dt * 8 + k8) * 64 + lane];
#pragma unroll
      for (int ct = 0; ct < 8; ++ct) {
        f32x4 acc = {0.f, 0.f, 0.f, 0.f};
#pragma unroll
        for (int k8 = 0; k8 < 8; ++k8) {
          int brow = ct * 16 + lr;
          bf16x8 xf = *reinterpret_cast<const bf16x8*>(
              Areg + brow * 512 + ((k8 * 64 + g * 16) ^ ((brow & 7) << 4)));
          acc = MFMA(wf[k8], xf, acc);
        }
        bf16x4 pb; pb[0]=(__bf16)acc[0]; pb[1]=(__bf16)acc[1];
        pb[2]=(__bf16)acc[2]; pb[3]=(__bf16)acc[3];
        *reinterpret_cast<bf16x4*>(
            Breg + ct * 8192 + w * 1024 +
            (lr + 16 * (2 * dth + (g >> 1))) * 16 + (g & 1) * 8) = pb;
      }
    }
  };
  // v projection half: ct 0..3 -> dest=Creg (kk8 0,1); ct 4..7 -> dest=Areg-low
  auto projV = [&](int half, char* dest) {
    const bf16x8* wp = reinterpret_cast<const bf16x8*>(wvp);
#pragma unroll
    for (int dth = 0; dth < 2; ++dth) {
      int dt = 2 * w + dth;
      bf16x8 wf[8];
#pragma unroll
      for (int k8 = 0; k8 < 8; ++k8) wf[k8] = wp[(dt * 8 + k8) * 64 + lane];
#pragma unroll
      for (int ctl = 0; ctl < 4; ++ctl) {
        int ct = half * 4 + ctl;
        f32x4 acc = {0.f, 0.f, 0.f, 0.f};
#pragma unroll
        for (int k8 = 0; k8 < 8; ++k8) {
          int brow = ct * 16 + lr;
          bf16x8 xf = *reinterpret_cast<const bf16x8*>(
              Areg + brow * 512 + ((k8 * 64 + g * 16) ^ ((brow & 7) << 4)));
          acc = MFMA(wf[k8], xf, acc);
        }
        // element (d = dt*16+4g+j, k2 = ct*16+lr)
        int kk8loc = (ct >> 1) & 1;
        char* bse = dest + (dt * 2 + kk8loc) * 1024 +
                    (16 * ((ct * 2 + (lr >> 3)) & 3)) * 16 + (lr & 7) * 2;
#pragma unroll
        for (int j = 0; j < 4; ++j)
          *reinterpret_cast<__bf16*>(bse + (4 * g + j) * 16) = (__bf16)acc[j];
      }
    }
  };

  // ---- phase 1: q
  stageX(Xq);
  __syncthreads();                               // b1
  projQK(wqp);
  __syncthreads();                               // b2
  bf16x8 af[8];                                  // projected q, A-frags (regs)
#pragma unroll
  for (int k8 = 0; k8 < 8; ++k8)
    af[k8] = *reinterpret_cast<const bf16x8*>(Breg + w * 8192 + k8 * 1024 + lane * 16);
  stageX(Xk);
  __syncthreads();                               // b3
  projQK(wkp);                                   // k-pack image -> Breg
  __syncthreads();                               // b4

  // ---- phase 2: issue Xv loads early, mask prefetch, QK^T, flush Xv stage
  float4 vreg[16];
#pragma unroll
  for (int i = 0; i < 16; ++i) {
    int f = i * 512 + t;
    int row = f >> 6, c4 = f & 63;
    vreg[i] = *reinterpret_cast<const float4*>(
        Xv + ((size_t)(n * 8192 + row * 64 + s)) * 256 + c4 * 4);
  }
  int mreg[8][4];
#pragma unroll
  for (int ct = 0; ct < 8; ++ct)
#pragma unroll
    for (int j = 0; j < 4; ++j)
      mreg[ct][j] = mask[((size_t)n * 128 + w * 16 + 4 * g + j) * 128 + ct * 16 + lr];
  f32x4 sacc[8];
#pragma unroll
  for (int ct = 0; ct < 8; ++ct) {
    f32x4 a = {0.f, 0.f, 0.f, 0.f};
#pragma unroll
    for (int k8 = 0; k8 < 8; ++k8)
      a = MFMA(af[k8],
               *reinterpret_cast<const bf16x8*>(Breg + ct * 8192 + k8 * 1024 + lane * 16),
               a);
    sacc[ct] = a;
  }
#pragma unroll
  for (int i = 0; i < 16; ++i) {
    int f = i * 512 + t;
    int row = f >> 6, c4 = f & 63;
    float4 v = vreg[i];
    bf16x4 b; b[0]=(__bf16)v.x; b[1]=(__bf16)v.y; b[2]=(__bf16)v.z; b[3]=(__bf16)v.w;
    *reinterpret_cast<bf16x4*>(Areg + row * 512 + ((c4 * 8) ^ ((row & 7) << 4))) = b;
  }
  __syncthreads();                               // b5

  // ---- phase 3: softmax in regs (row q = w*16+4g+j spans ct x lr)
  float p[8][4];
#pragma unroll
  for (int j = 0; j < 4; ++j) {
    float mx = -3e38f;
#pragma unroll
    for (int ct = 0; ct < 8; ++ct) {
      float sv = mreg[ct][j] ? sacc[ct][j] * 0.0625f : -6.25e18f;  // -1e20/16
      p[ct][j] = sv;
      mx = fmaxf(mx, sv);
    }
#pragma unroll
    for (int o = 1; o < 16; o <<= 1) mx = fmaxf(mx, __shfl_xor(mx, o));
    float sum = 0.f;
#pragma unroll
    for (int ct = 0; ct < 8; ++ct) {
      float e = __expf(p[ct][j] - mx);
      p[ct][j] = e;
      sum += e;
    }
#pragma unroll
    for (int o = 1; o < 16; o <<= 1) sum += __shfl_xor(sum, o);
    float inv = 1.f / sum;
#pragma unroll
    for (int ct = 0; ct < 8; ++ct) p[ct][j] *= inv;
  }
  // P image (wave-local, Breg + w*4096), then hoist A-frags
#pragma unroll
  for (int ct = 0; ct < 8; ++ct) {
    char* bse = Breg + w * 4096 + (ct >> 1) * 1024 +
                (16 * ((ct * 2 + (lr >> 3)) & 3)) * 16 + (lr & 7) * 2;
#pragma unroll
    for (int j = 0; j < 4; ++j)
      *reinterpret_cast<__bf16*>(bse + (4 * g + j) * 16) = (__bf16)p[ct][j];
  }
  bf16x8 pa[4];
#pragma unroll
  for (int kk8 = 0; kk8 < 4; ++kk8)
    pa[kk8] = *reinterpret_cast<const bf16x8*>(Breg + w * 4096 + kk8 * 1024 + lane * 16);
  projV(0, Creg);                                // reads Areg rows 0..63
  __syncthreads();                               // b6
  projV(1, Areg);                                // reads rows 64..127, writes A-low
  __syncthreads();                               // b7

  // ---- phase 4: PV -> O image (wave-local, Breg + w*8192, A-frag layout)
#pragma unroll
  for (int dt = 0; dt < 16; ++dt) {
    f32x4 acc = {0.f, 0.f, 0.f, 0.f};
#pragma unroll
    for (int kk8 = 0; kk8 < 4; ++kk8) {
      const char* vb = (kk8 < 2) ? (Creg + (dt * 2 + kk8) * 1024)
                                 : (Areg + (dt * 2 + kk8 - 2) * 1024);
      acc = MFMA(pa[kk8], *reinterpret_cast<const bf16x8*>(vb + lane * 16), acc);
    }
    char* bse = Breg + w * 8192 + (dt >> 1) * 1024 +
                (16 * ((dt * 2 + (lr >> 3)) & 3)) * 16 + (lr & 7) * 2;
#pragma unroll
    for (int j = 0; j < 4; ++j)
      *reinterpret_cast<__bf16*>(bse + (4 * g + j) * 16) = (__bf16)acc[j];
  }

  // ---- phase 5: out = O @ WoSum + bo (oa wave-local; wop via L1/L2)
  bf16x8 oa[8];
#pragma unroll
  for (int k8 = 0; k8 < 8; ++k8)
    oa[k8] = *reinterpret_cast<const bf16x8*>(Breg + w * 8192 + k8 * 1024 + lane * 16);
  const bf16x8* wo = reinterpret_cast<const bf16x8*>(wop);
#pragma unroll
  for (int ct = 0; ct < 16; ++ct) {
    f32x4 acc = {0.f, 0.f, 0.f, 0.f};
#pragma unroll
    for (int k8 = 0; k8 < 8; ++k8)
      acc = MFMA(oa[k8], wo[(ct * 8 + k8) * 64 + lane], acc);
    int e = ct * 16 + lr;
    float bias = bo[e];
#pragma unroll
    for (int j = 0; j < 4; ++j) {
      int q = w * 16 + 4 * g + j;
      out[((size_t)n * 8192 + q * 64 + s) * 256 + e] = acc[j] + bias;
    }
  }
}

extern "C" void kernel_launch(void* const* d_in, const int* in_sizes, int n_in,
                              void* d_out, int out_size, void* d_ws, size_t ws_size,
                              hipStream_t stream) {
  const float* values = (const float*)d_in[0];
  const float* keys   = (const float*)d_in[1];
  const float* query  = (const float*)d_in[2];
  const int*   mask   = (const int*)d_in[3];
  const float* Wq     = (const float*)d_in[4];
  const float* Wk     = (const float*)d_in[5];
  const float* Wv     = (const float*)d_in[6];
  const float* Wo     = (const float*)d_in[7];
  const float* bo     = (const float*)d_in[8];
  float* out = (float*)d_out;

  char* w = (char*)d_ws;
  __bf16* wqp = (__bf16*)w; w += 131072;   // [16 ct][8 k8][64][8]
  __bf16* wkp = (__bf16*)w; w += 131072;
  __bf16* wvp = (__bf16*)w; w += 131072;
  __bf16* wop = (__bf16*)w; w += 131072;

  prep_pack<<<256, 256, 0, stream>>>(Wq, Wk, Wv, Wo, wqp, wkp, wvp, wop);
  fused_attn<<<256, 512, 163840, stream>>>(values, keys, query, mask,
                                           wqp, wkp, wvp, wop, bo, out);
}

// Round 7
// 47.683 us; speedup vs baseline: 9.1131x; 1.2087x over previous
//
#include <hip/hip_runtime.h>
#include <hip/hip_bf16.h>

// N=4, L=128, S=64, D=256, H=8. Heads collapse => per slice sl=n*64+s:
//   out = softmax((Xq Wq)(Xk Wk)^T/16 + mask) (Xv Wv) @ WoSum + bo
// ONE fused kernel, one block (512 thr / 8 waves, 160KB LDS) per slice.
// Frag convention: [tile][k8-chunk][lane(64)][j(8)]: lane l = row/col (l&15),
// k = k8*32+(l>>4)*8+j. A/B share the lane->k map (HW perm cancels);
// D layout row=4*(lane>>4)+j, col=lane&15.
// Round-7 changes (LDS-pipe bound at r6: ~4k b128 reads/CU):
//  - xf[8] hoisted out of the dth loop in projQK/projV (halves proj LDS reads)
//  - out-projection operand swap: wop as A in regs (16 global loads, was 128),
//    O-image as B from LDS, float4 stores with fused bias
//  - staging writes b128 (was b64); V-weight frags loaded once
// LDS: A [0,64K) staged X -> v-pack kk8{2,3} in A-low
//      B [64K,128K) q-image -> k-pack -> P(per-wave 4K) -> O-image(per-wave 8K)
//      C [128K,160K) v-pack kk8{0,1}

using bf16x4 = __attribute__((ext_vector_type(4))) __bf16;
using bf16x8 = __attribute__((ext_vector_type(8))) __bf16;
using f32x4  = __attribute__((ext_vector_type(4))) float;

#define MFMA(a, b, c) __builtin_amdgcn_mfma_f32_16x16x32_bf16((a), (b), (c), 0, 0, 0)

// ---------------------------------------------------------------- prep packs
// pack[ct][k8][lane][j] = W[d][e], e = ct*16+(lane&15), d = k8*32+(lane>>4)*8+j
__global__ __launch_bounds__(256) void prep_pack(
    const float* __restrict__ Wq, const float* __restrict__ Wk,
    const float* __restrict__ Wv, const float* __restrict__ Wo,
    __bf16* __restrict__ wqp, __bf16* __restrict__ wkp,
    __bf16* __restrict__ wvp, __bf16* __restrict__ wop) {
  int idx = blockIdx.x * 256 + threadIdx.x;       // [0, 65536)
  int j = idx & 7, lane = (idx >> 3) & 63, k8 = (idx >> 9) & 7, ct = idx >> 12;
  int e = ct * 16 + (lane & 15);
  int d = k8 * 32 + (lane >> 4) * 8 + j;
  wqp[idx] = (__bf16)Wq[d * 256 + e];
  wkp[idx] = (__bf16)Wk[d * 256 + e];
  wvp[idx] = (__bf16)Wv[d * 256 + e];
  float s = 0.f;
#pragma unroll
  for (int h = 0; h < 8; ++h) s += Wo[(h * 256 + d) * 256 + e];
  wop[idx] = (__bf16)s;
}

// ---------------------------------------------------------------- fused
__global__ __launch_bounds__(512, 2) void fused_attn(
    const float* __restrict__ Xv, const float* __restrict__ Xk,
    const float* __restrict__ Xq, const int* __restrict__ mask,
    const __bf16* __restrict__ wqp, const __bf16* __restrict__ wkp,
    const __bf16* __restrict__ wvp, const __bf16* __restrict__ wop,
    const float* __restrict__ bo, float* __restrict__ out) {
  extern __shared__ char lds[];
  char* Areg = lds;                // 64KB
  char* Breg = lds + 65536;        // 64KB
  char* Creg = lds + 131072;       // 32KB
  const int t = threadIdx.x, lane = t & 63, w = t >> 6;
  const int lr = lane & 15, g = lane >> 4;
  const int sl = blockIdx.x, n = sl >> 6, s = sl & 63;

  // ---- staging helpers: 128-row [row][256] fp32 slice -> Areg swizzled bf16
  auto fill = [&](const float* __restrict__ X, float4* vr) {
#pragma unroll
    for (int i = 0; i < 8; ++i) {
      int f8 = i * 512 + t, row = f8 >> 5, c8 = f8 & 31;
      const float* src = X + ((size_t)(n * 8192 + row * 64 + s)) * 256 + c8 * 8;
      vr[2 * i]     = *reinterpret_cast<const float4*>(src);
      vr[2 * i + 1] = *reinterpret_cast<const float4*>(src + 4);
    }
  };
  auto flushv = [&](const float4* vr) {
#pragma unroll
    for (int i = 0; i < 8; ++i) {
      int f8 = i * 512 + t, row = f8 >> 5, c8 = f8 & 31;
      bf16x8 b;
      b[0]=(__bf16)vr[2*i].x;   b[1]=(__bf16)vr[2*i].y;
      b[2]=(__bf16)vr[2*i].z;   b[3]=(__bf16)vr[2*i].w;
      b[4]=(__bf16)vr[2*i+1].x; b[5]=(__bf16)vr[2*i+1].y;
      b[6]=(__bf16)vr[2*i+1].z; b[7]=(__bf16)vr[2*i+1].w;
      *reinterpret_cast<bf16x8*>(
          Areg + row * 512 + ((c8 * 16) ^ ((row & 7) << 4))) = b;
    }
  };

  // weights-in-regs projection: D[d=32w+16dth+4g+j][q=ct*16+lr] -> q/k image
  // in Breg, frag layout [ct][k8=w][slot][j8]. xf read ONCE per ct (both dth).
  auto projQK = [&](const __bf16* __restrict__ wpk) {
    const bf16x8* wp = reinterpret_cast<const bf16x8*>(wpk);
    bf16x8 wf0[8], wf1[8];
#pragma unroll
    for (int k8 = 0; k8 < 8; ++k8) {
      wf0[k8] = wp[((2 * w)     * 8 + k8) * 64 + lane];
      wf1[k8] = wp[((2 * w + 1) * 8 + k8) * 64 + lane];
    }
#pragma unroll
    for (int ct = 0; ct < 8; ++ct) {
      bf16x8 xf[8];
#pragma unroll
      for (int k8 = 0; k8 < 8; ++k8) {
        int brow = ct * 16 + lr;
        xf[k8] = *reinterpret_cast<const bf16x8*>(
            Areg + brow * 512 + ((k8 * 64 + g * 16) ^ ((brow & 7) << 4)));
      }
      f32x4 a0 = {0.f,0.f,0.f,0.f}, a1 = {0.f,0.f,0.f,0.f};
#pragma unroll
      for (int k8 = 0; k8 < 8; ++k8) {
        a0 = MFMA(wf0[k8], xf[k8], a0);
        a1 = MFMA(wf1[k8], xf[k8], a1);
      }
      bf16x4 p0, p1;
#pragma unroll
      for (int j = 0; j < 4; ++j) { p0[j] = (__bf16)a0[j]; p1[j] = (__bf16)a1[j]; }
      *reinterpret_cast<bf16x4*>(
          Breg + ct * 8192 + w * 1024 + (lr + 16 * (0 + (g >> 1))) * 16 + (g & 1) * 8) = p0;
      *reinterpret_cast<bf16x4*>(
          Breg + ct * 8192 + w * 1024 + (lr + 16 * (2 + (g >> 1))) * 16 + (g & 1) * 8) = p1;
    }
  };

  // ---- phase 1: q projection (prefetch Xk under the MFMAs)
  {
    float4 vr[16];
    fill(Xq, vr);
    flushv(vr);
  }
  __syncthreads();                               // b1
  float4 vrp[16];
  fill(Xk, vrp);                                 // prefetch Xk
  projQK(wqp);
  __syncthreads();                               // b2
  bf16x8 af[8];                                  // projected q A-frags (regs)
#pragma unroll
  for (int k8 = 0; k8 < 8; ++k8)
    af[k8] = *reinterpret_cast<const bf16x8*>(Breg + w * 8192 + k8 * 1024 + lane * 16);
  flushv(vrp);                                   // Xk -> Areg
  __syncthreads();                               // b3

  // ---- phase 2: k projection (prefetch Xv under the MFMAs)
  fill(Xv, vrp);                                 // prefetch Xv
  projQK(wkp);                                   // k-pack -> Breg
  __syncthreads();                               // b4

  // ---- phase 3: QK^T (+ mask prefetch), then flush Xv stage
  int mreg[8][4];
#pragma unroll
  for (int ct = 0; ct < 8; ++ct)
#pragma unroll
    for (int j = 0; j < 4; ++j)
      mreg[ct][j] = mask[((size_t)n * 128 + w * 16 + 4 * g + j) * 128 + ct * 16 + lr];
  f32x4 sacc[8];
#pragma unroll
  for (int ct = 0; ct < 8; ++ct) {
    bf16x8 bfr[8];
#pragma unroll
    for (int k8 = 0; k8 < 8; ++k8)
      bfr[k8] = *reinterpret_cast<const bf16x8*>(Breg + ct * 8192 + k8 * 1024 + lane * 16);
    f32x4 a = {0.f,0.f,0.f,0.f};
#pragma unroll
    for (int k8 = 0; k8 < 8; ++k8) a = MFMA(af[k8], bfr[k8], a);
    sacc[ct] = a;
  }
  flushv(vrp);                                   // Xv -> Areg
  __syncthreads();                               // b5

  // ---- phase 4: softmax in regs (row q = w*16+4g+j spans ct x lr)
  float p[8][4];
#pragma unroll
  for (int j = 0; j < 4; ++j) {
    float mx = -3e38f;
#pragma unroll
    for (int ct = 0; ct < 8; ++ct) {
      float sv = mreg[ct][j] ? sacc[ct][j] * 0.0625f : -6.25e18f;  // -1e20/16
      p[ct][j] = sv;
      mx = fmaxf(mx, sv);
    }
#pragma unroll
    for (int o = 1; o < 16; o <<= 1) mx = fmaxf(mx, __shfl_xor(mx, o));
    float sum = 0.f;
#pragma unroll
    for (int ct = 0; ct < 8; ++ct) {
      float e = __expf(p[ct][j] - mx);
      p[ct][j] = e;
      sum += e;
    }
#pragma unroll
    for (int o = 1; o < 16; o <<= 1) sum += __shfl_xor(sum, o);
    float inv = 1.f / sum;
#pragma unroll
    for (int ct = 0; ct < 8; ++ct) p[ct][j] *= inv;
  }
  // P image (wave-local, Breg + w*4096), then hoist A-frags
#pragma unroll
  for (int ct = 0; ct < 8; ++ct) {
    char* bse = Breg + w * 4096 + (ct >> 1) * 1024 +
                (16 * ((ct * 2 + (lr >> 3)) & 3)) * 16 + (lr & 7) * 2;
#pragma unroll
    for (int j = 0; j < 4; ++j)
      *reinterpret_cast<__bf16*>(bse + (4 * g + j) * 16) = (__bf16)p[ct][j];
  }
  bf16x8 pa[4];
#pragma unroll
  for (int kk8 = 0; kk8 < 4; ++kk8)
    pa[kk8] = *reinterpret_cast<const bf16x8*>(Breg + w * 4096 + kk8 * 1024 + lane * 16);

  // ---- phase 5: v projection, halves; wf loaded ONCE; xf once per ct
  {
    const bf16x8* wp = reinterpret_cast<const bf16x8*>(wvp);
    bf16x8 vf0[8], vf1[8];
#pragma unroll
    for (int k8 = 0; k8 < 8; ++k8) {
      vf0[k8] = wp[((2 * w)     * 8 + k8) * 64 + lane];
      vf1[k8] = wp[((2 * w + 1) * 8 + k8) * 64 + lane];
    }
#pragma unroll
    for (int half = 0; half < 2; ++half) {
      char* dest = half ? Areg : Creg;
#pragma unroll
      for (int ctl = 0; ctl < 4; ++ctl) {
        int ct = half * 4 + ctl;
        bf16x8 xf[8];
#pragma unroll
        for (int k8 = 0; k8 < 8; ++k8) {
          int brow = ct * 16 + lr;
          xf[k8] = *reinterpret_cast<const bf16x8*>(
              Areg + brow * 512 + ((k8 * 64 + g * 16) ^ ((brow & 7) << 4)));
        }
        f32x4 a0 = {0.f,0.f,0.f,0.f}, a1 = {0.f,0.f,0.f,0.f};
#pragma unroll
        for (int k8 = 0; k8 < 8; ++k8) {
          a0 = MFMA(vf0[k8], xf[k8], a0);
          a1 = MFMA(vf1[k8], xf[k8], a1);
        }
        int kk8loc = (ct >> 1) & 1;
#pragma unroll
        for (int dth = 0; dth < 2; ++dth) {
          const f32x4& ac = dth ? a1 : a0;
          char* bse = dest + ((2 * w + dth) * 2 + kk8loc) * 1024 +
                      (16 * ((ct * 2 + (lr >> 3)) & 3)) * 16 + (lr & 7) * 2;
#pragma unroll
          for (int j = 0; j < 4; ++j)
            *reinterpret_cast<__bf16*>(bse + (4 * g + j) * 16) = (__bf16)ac[j];
        }
      }
      __syncthreads();                           // b6 (after half0), b7 (after half1)
    }
  }

  // ---- phase 6: PV -> O image (wave-local, Breg + w*8192, frag layout)
#pragma unroll
  for (int dt = 0; dt < 16; ++dt) {
    f32x4 acc = {0.f,0.f,0.f,0.f};
#pragma unroll
    for (int kk8 = 0; kk8 < 4; ++kk8) {
      const char* vb = (kk8 < 2) ? (Creg + (dt * 2 + kk8) * 1024)
                                 : (Areg + (dt * 2 + kk8 - 2) * 1024);
      acc = MFMA(pa[kk8], *reinterpret_cast<const bf16x8*>(vb + lane * 16), acc);
    }
    char* bse = Breg + w * 8192 + (dt >> 1) * 1024 +
                (16 * ((dt * 2 + (lr >> 3)) & 3)) * 16 + (lr & 7) * 2;
#pragma unroll
    for (int j = 0; j < 4; ++j)
      *reinterpret_cast<__bf16*>(bse + (4 * g + j) * 16) = (__bf16)acc[j];
  }
  __syncthreads();                               // b8 (out reads all qt images)

  // ---- phase 7: out = O @ WoSum + bo. wop as A in regs (2 ct tiles/wave),
  // O-frags as B from LDS (A-frag layout == B-frag layout: lane->q, elems->d).
  {
    const bf16x8* wo = reinterpret_cast<const bf16x8*>(wop);
    bf16x8 of0[8], of1[8];
#pragma unroll
    for (int k8 = 0; k8 < 8; ++k8) {
      of0[k8] = wo[((2 * w)     * 8 + k8) * 64 + lane];
      of1[k8] = wo[((2 * w + 1) * 8 + k8) * 64 + lane];
    }
    float4 bias0 = *reinterpret_cast<const float4*>(bo + (2 * w)     * 16 + 4 * g);
    float4 bias1 = *reinterpret_cast<const float4*>(bo + (2 * w + 1) * 16 + 4 * g);
#pragma unroll
    for (int qt = 0; qt < 8; ++qt) {
      bf16x8 bfr[8];
#pragma unroll
      for (int k8 = 0; k8 < 8; ++k8)
        bfr[k8] = *reinterpret_cast<const bf16x8*>(Breg + qt * 8192 + k8 * 1024 + lane * 16);
      f32x4 a0 = {0.f,0.f,0.f,0.f}, a1 = {0.f,0.f,0.f,0.f};
#pragma unroll
      for (int k8 = 0; k8 < 8; ++k8) {
        a0 = MFMA(of0[k8], bfr[k8], a0);
        a1 = MFMA(of1[k8], bfr[k8], a1);
      }
      int q = qt * 16 + lr;
      float* orow = out + ((size_t)n * 8192 + q * 64 + s) * 256;
      float4 o0, o1;
      o0.x = a0[0] + bias0.x; o0.y = a0[1] + bias0.y;
      o0.z = a0[2] + bias0.z; o0.w = a0[3] + bias0.w;
      o1.x = a1[0] + bias1.x; o1.y = a1[1] + bias1.y;
      o1.z = a1[2] + bias1.z; o1.w = a1[3] + bias1.w;
      *reinterpret_cast<float4*>(orow + (2 * w)     * 16 + 4 * g) = o0;
      *reinterpret_cast<float4*>(orow + (2 * w + 1) * 16 + 4 * g) = o1;
    }
  }
}

extern "C" void kernel_launch(void* const* d_in, const int* in_sizes, int n_in,
                              void* d_out, int out_size, void* d_ws, size_t ws_size,
                              hipStream_t stream) {
  const float* values = (const float*)d_in[0];
  const float* keys   = (const float*)d_in[1];
  const float* query  = (const float*)d_in[2];
  const int*   mask   = (const int*)d_in[3];
  const float* Wq     = (const float*)d_in[4];
  const float* Wk     = (const float*)d_in[5];
  const float* Wv     = (const float*)d_in[6];
  const float* Wo     = (const float*)d_in[7];
  const float* bo     = (const float*)d_in[8];
  float* out = (float*)d_out;

  char* w = (char*)d_ws;
  __bf16* wqp = (__bf16*)w; w += 131072;   // [16 ct][8 k8][64][8]
  __bf16* wkp = (__bf16*)w; w += 131072;
  __bf16* wvp = (__bf16*)w; w += 131072;
  __bf16* wop = (__bf16*)w; w += 131072;

  prep_pack<<<256, 256, 0, stream>>>(Wq, Wk, Wv, Wo, wqp, wkp, wvp, wop);
  fused_attn<<<256, 512, 163840, stream>>>(values, keys, query, mask,
                                           wqp, wkp, wvp, wop, bo, out);
}